// Round 15
// baseline (2004.344 us; speedup 1.0000x reference)
//
#include <hip/hip_runtime.h>
#include <cfloat>

namespace {

constexpr int Bb    = 4;
constexpr int Nn    = 4096;
constexpr int Cc    = 96;
constexpr int Ll    = 4;           // hops+1 slots
constexpr int NPTS  = Bb * Nn;     // 16384
constexpr int KP    = 100;         // padded LDS row stride (floats) for fp32 gemm
constexpr int CS    = 2;           // column splits of the db dimension
constexpr int TK    = 12;          // per-lane candidates
constexpr int NCROW = CS * 4 * TK; // 96 candidates per row
constexpr int LP    = 104;         // bf16 LDS row pitch (208 B)

typedef __attribute__((ext_vector_type(8))) short bf16x8;
typedef __attribute__((ext_vector_type(4))) float f32x4;

// RNE fp32 -> bf16 (candidate ranking only)
__device__ inline ushort f2bf(float x) {
    unsigned u = __float_as_uint(x);
    return (ushort)((u + 0x7FFF + ((u >> 16) & 1)) >> 16);
}

// lexicographic (value asc, index asc) sorted-insert into top-T
template<int T>
__device__ inline void lexins(float v, int vi, float (&bd)[T], int (&bi)[T]) {
    if (v < bd[T - 1] || (v == bd[T - 1] && vi < bi[T - 1])) {
        #pragma unroll
        for (int t = 0; t < T; ++t) {
            if (v < bd[t] || (v == bd[t] && vi < bi[t])) {
                float tv = bd[t]; bd[t] = v;  v  = tv;
                int   ti = bi[t]; bi[t] = vi; vi = ti;
            }
        }
    }
}

// ---- initial: xyz->A32 slot0 copy + np-mimic sq (pairwise-8) + bf16 cvt ----
__global__ __launch_bounds__(64) void sqcvt_kernel(const float* __restrict__ src0,
                                                   float* __restrict__ A32,
                                                   float* __restrict__ sqnp,
                                                   ushort* __restrict__ A16) {
    const int p = blockIdx.x * 64 + threadIdx.x;
    const float4* xs = reinterpret_cast<const float4*>(src0 + (size_t)p * Cc);
    float4 x[24];
    #pragma unroll
    for (int i = 0; i < 24; ++i) x[i] = xs[i];
    {
        float4* d = reinterpret_cast<float4*>(A32 + (size_t)p * Ll * Cc);
        #pragma unroll
        for (int i = 0; i < 24; ++i) d[i] = x[i];
    }
    // numpy pairwise-8 tree over fl(x*x)
    float r[8];
    r[0] = __fmul_rn(x[0].x, x[0].x); r[1] = __fmul_rn(x[0].y, x[0].y);
    r[2] = __fmul_rn(x[0].z, x[0].z); r[3] = __fmul_rn(x[0].w, x[0].w);
    r[4] = __fmul_rn(x[1].x, x[1].x); r[5] = __fmul_rn(x[1].y, x[1].y);
    r[6] = __fmul_rn(x[1].z, x[1].z); r[7] = __fmul_rn(x[1].w, x[1].w);
    #pragma unroll
    for (int g = 1; g < 12; ++g) {
        float4 va = x[2 * g], vb = x[2 * g + 1];
        r[0] = __fadd_rn(r[0], __fmul_rn(va.x, va.x));
        r[1] = __fadd_rn(r[1], __fmul_rn(va.y, va.y));
        r[2] = __fadd_rn(r[2], __fmul_rn(va.z, va.z));
        r[3] = __fadd_rn(r[3], __fmul_rn(va.w, va.w));
        r[4] = __fadd_rn(r[4], __fmul_rn(vb.x, vb.x));
        r[5] = __fadd_rn(r[5], __fmul_rn(vb.y, vb.y));
        r[6] = __fadd_rn(r[6], __fmul_rn(vb.z, vb.z));
        r[7] = __fadd_rn(r[7], __fmul_rn(vb.w, vb.w));
    }
    float L = __fadd_rn(__fadd_rn(r[0], r[1]), __fadd_rn(r[2], r[3]));
    float R = __fadd_rn(__fadd_rn(r[4], r[5]), __fadd_rn(r[6], r[7]));
    sqnp[p] = __fadd_rn(L, R);
    #pragma unroll
    for (int j = 0; j < 12; ++j) {
        float4 v0 = x[2 * j], v1 = x[2 * j + 1];
        uint4 o;
        o.x = (unsigned)f2bf(v0.x) | ((unsigned)f2bf(v0.y) << 16);
        o.y = (unsigned)f2bf(v0.z) | ((unsigned)f2bf(v0.w) << 16);
        o.z = (unsigned)f2bf(v1.x) | ((unsigned)f2bf(v1.y) << 16);
        o.w = (unsigned)f2bf(v1.z) | ((unsigned)f2bf(v1.w) << 16);
        *reinterpret_cast<uint4*>(A16 + (size_t)p * 96 + j * 8) = o;
    }
}

// ---- MFMA candidate pass (R11-proven): chunk=64, LDS double-buffer staging ----
__global__ __launch_bounds__(256) void knn_mfma_kernel(const ushort* __restrict__ A16,
                                                       const float* __restrict__ sqnp,
                                                       int* __restrict__ cand) {
    __shared__ ushort qt[64 * LP];
    __shared__ ushort dbt[2][64 * LP];
    __shared__ float  sqf[2][64];
    __shared__ float  klds[256 * 20];

    const int q0    = blockIdx.x * 64;
    const int cs    = blockIdx.y;
    const int pbase = (q0 >> 12) << 12;
    const int col0  = cs * (Nn / CS);
    const int tid   = threadIdx.x;
    const int w     = tid >> 6;
    const int l     = tid & 63;
    constexpr int NCH = (Nn / CS) / 64;

    {
        int r = tid >> 2, q = tid & 3;
        const uint4* s = reinterpret_cast<const uint4*>(A16 + (size_t)(q0 + r) * 96 + q * 24);
        uint4* d = reinterpret_cast<uint4*>(qt + r * LP + q * 24);
        d[0] = s[0]; d[1] = s[1]; d[2] = s[2];
        const uint4* s2 = reinterpret_cast<const uint4*>(
            A16 + (size_t)(pbase + col0 + r) * 96 + q * 24);
        uint4* d2 = reinterpret_cast<uint4*>(dbt[0] + r * LP + q * 24);
        d2[0] = s2[0]; d2[1] = s2[1]; d2[2] = s2[2];
    }
    if (tid < 64) sqf[0][tid] = -0.5f * sqnp[pbase + col0 + tid];
    __syncthreads();

    const int qrow = w * 16 + (l & 15);
    const int koff = (l >> 4) * 8;
    const int lb4  = (l >> 4) * 4;
    bf16x8 bq[3];
    #pragma unroll
    for (int s = 0; s < 3; ++s)
        bq[s] = *reinterpret_cast<const bf16x8*>(qt + qrow * LP + koff + 32 * s);

    float bd[TK]; int bi[TK];
    #pragma unroll
    for (int t = 0; t < TK; ++t) { bd[t] = -FLT_MAX; bi[t] = 0x7fffffff; }
    float kd = -FLT_MAX;

    for (int c = 0; c < NCH; ++c) {
        const int buf = c & 1;
        if (c + 1 < NCH) {
            int r = tid >> 2, q = tid & 3;
            const uint4* s = reinterpret_cast<const uint4*>(
                A16 + (size_t)(pbase + col0 + (c + 1) * 64 + r) * 96 + q * 24);
            uint4* d = reinterpret_cast<uint4*>(dbt[buf ^ 1] + r * LP + q * 24);
            d[0] = s[0]; d[1] = s[1]; d[2] = s[2];
            if (tid < 64) sqf[buf ^ 1][tid] = -0.5f * sqnp[pbase + col0 + (c + 1) * 64 + tid];
        }

        f32x4 acc[4];
        #pragma unroll
        for (int sub = 0; sub < 4; ++sub) {
            acc[sub] = *reinterpret_cast<const f32x4*>(&sqf[buf][sub * 16 + lb4]);
            #pragma unroll
            for (int s = 0; s < 3; ++s) {
                bf16x8 a = *reinterpret_cast<const bf16x8*>(
                    dbt[buf] + (sub * 16 + (l & 15)) * LP + koff + 32 * s);
                acc[sub] = __builtin_amdgcn_mfma_f32_16x16x32_bf16(a, bq[s], acc[sub], 0, 0, 0);
            }
        }

        unsigned mask = 0;
        #pragma unroll
        for (int sub = 0; sub < 4; ++sub) {
            float m = fmaxf(fmaxf(acc[sub][0], acc[sub][1]),
                            fmaxf(acc[sub][2], acc[sub][3]));
            if (m > kd) {
                *reinterpret_cast<f32x4*>(&klds[tid * 20 + sub * 4]) = acc[sub];
                unsigned mb = (acc[sub][0] > kd ? 1u : 0u) |
                              (acc[sub][1] > kd ? 2u : 0u) |
                              (acc[sub][2] > kd ? 4u : 0u) |
                              (acc[sub][3] > kd ? 8u : 0u);
                mask |= mb << (sub * 4);
            }
        }
        const int cbase = col0 + c * 64 + lb4;
        while (mask) {
            int s = __builtin_ctz(mask); mask &= mask - 1;
            float v = klds[tid * 20 + s];
            int vi = cbase + ((s >> 2) << 4) + (s & 3);
            if (v > kd) {
                #pragma unroll
                for (int t = 0; t < TK; ++t) {
                    if (v > bd[t] || (v == bd[t] && vi < bi[t])) {
                        float tv = bd[t]; bd[t] = v;  v  = tv;
                        int   ti = bi[t]; bi[t] = vi; vi = ti;
                    }
                }
                kd = bd[TK - 1];
            }
        }
        __syncthreads();
    }

    const int qg = q0 + qrow;
    #pragma unroll
    for (int t = 0; t < TK; ++t)
        cand[(size_t)qg * NCROW + (cs * 4 + (l >> 4)) * TK + t] = bi[t];
}

// ---- fused hop tail: np-exact rescore -> stable top-8 -> np mean -> np MLP1 ->
//      np MLP2 -> write A32 slot h+1 + np sq + bf16 cvt (all for 32 queries/block).
// nb/h1 live only in LDS; all np summation chains bit-identical to the split
// kernels (mean tree, sequential-k FMA chains, pairwise-8 sq tree, RNE bf16).
// block 256 = 32 queries x 8 subs; grid NPTS/32.
__global__ __launch_bounds__(256) void hoptail_kernel(float* __restrict__ A32,
                                                      float* __restrict__ sqnp,
                                                      const int* __restrict__ cand,
                                                      const float* __restrict__ W1,
                                                      const float* __restrict__ b1,
                                                      const float* __restrict__ W2,
                                                      const float* __restrict__ b2,
                                                      ushort* __restrict__ A16, int h) {
    __shared__ float sc[32][100];    // d2 scores; later reused for MLP2 outputs
    __shared__ int   sidx[32][8];
    __shared__ float nbl[32][100];   // neighbor mean (pitch 100: f4-aligned, bank-spread)
    __shared__ float h1l[32][196];   // MLP1 out (pitch 196: f4-aligned, bank-spread)
    const int tid  = threadIdx.x;
    const int qloc = tid >> 3, sub = tid & 7;
    const int p    = blockIdx.x * 32 + qloc;
    const int base = (p >> 12) << 12;
    const int* cp  = cand + (size_t)p * NCROW;

    // ---- phase 1: np-exact rescore of 12 candidates (xn in registers) ----
    {
        float4 xnr[24];
        const float4* xs = reinterpret_cast<const float4*>(A32 + (size_t)(p * Ll + h) * Cc);
        #pragma unroll
        for (int i = 0; i < 24; ++i) xnr[i] = xs[i];
        const float sqn = sqnp[p];
        #pragma unroll
        for (int c = 0; c < NCROW / 8; ++c) {
            int m = cp[sub * (NCROW / 8) + c];
            const float4* xm = reinterpret_cast<const float4*>(
                A32 + (size_t)((base + m) * Ll + h) * Cc);
            // np einsum dot: SSE SOP — 4-lane mul+add accumulators, hadd combine
            float l0 = 0.f, l1 = 0.f, l2 = 0.f, l3 = 0.f;
            #pragma unroll
            for (int t = 0; t < 24; ++t) {
                float4 a = xnr[t], b = xm[t];
                l0 = __fadd_rn(l0, __fmul_rn(a.x, b.x));
                l1 = __fadd_rn(l1, __fmul_rn(a.y, b.y));
                l2 = __fadd_rn(l2, __fmul_rn(a.z, b.z));
                l3 = __fadd_rn(l3, __fmul_rn(a.w, b.w));
            }
            float dot = __fadd_rn(__fadd_rn(l0, l1), __fadd_rn(l2, l3));
            // np: d2 = fl(fl(sq_n + sq_m) - fl(2*dot))
            sc[qloc][sub * (NCROW / 8) + c] =
                __fsub_rn(__fadd_rn(sqn, sqnp[base + m]), __fmul_rn(2.0f, dot));
        }
    }
    __syncthreads();

    // ---- phase 2: stable top-8 by (d2, idx) — lax.top_k tie semantics ----
    if (sub == 0) {
        float sd[8]; int si[8];
        #pragma unroll
        for (int t = 0; t < 8; ++t) { sd[t] = FLT_MAX; si[t] = 0x7fffffff; }
        #pragma unroll 1
        for (int c = 0; c < NCROW; ++c) lexins<8>(sc[qloc][c], cp[c], sd, si);
        #pragma unroll
        for (int t = 0; t < 8; ++t) sidx[qloc][t] = si[t];
    }
    __syncthreads();

    // ---- phase 3: np-mimic mean (pairwise-8 tree, x0.125) -> nbl LDS ----
    {
        float4 rv[8][3];
        #pragma unroll
        for (int k = 0; k < 8; ++k) {
            const float4* rs = reinterpret_cast<const float4*>(
                A32 + (size_t)((base + sidx[qloc][k]) * Ll + h) * Cc + sub * 12);
            rv[k][0] = rs[0]; rv[k][1] = rs[1]; rv[k][2] = rs[2];
        }
        float4* dst = reinterpret_cast<float4*>(&nbl[qloc][sub * 12]);
        #pragma unroll
        for (int g = 0; g < 3; ++g) {
            float4 o;
            #define NPMEAN(comp) { \
                float L_ = __fadd_rn(__fadd_rn(rv[0][g].comp, rv[1][g].comp), \
                                     __fadd_rn(rv[2][g].comp, rv[3][g].comp)); \
                float R_ = __fadd_rn(__fadd_rn(rv[4][g].comp, rv[5][g].comp), \
                                     __fadd_rn(rv[6][g].comp, rv[7][g].comp)); \
                o.comp = __fmul_rn(__fadd_rn(L_, R_), 0.125f); }
            NPMEAN(x) NPMEAN(y) NPMEAN(z) NPMEAN(w)
            #undef NPMEAN
            dst[g] = o;
        }
    }
    __syncthreads();

    // ---- phase 4: np MLP1 (192 outs, K=96, sequential-k FMA + leaky) ----
    #pragma unroll 2
    for (int jj = 0; jj < 24; ++jj) {
        const int j = sub * 24 + jj;
        const float* wr = W1 + (size_t)j * 96;
        float acc = 0.f;
        #pragma unroll
        for (int k4 = 0; k4 < 24; ++k4) {
            float4 wv = *reinterpret_cast<const float4*>(wr + k4 * 4);
            float4 av = *reinterpret_cast<const float4*>(&nbl[qloc][k4 * 4]);
            acc = __builtin_fmaf(av.x, wv.x, acc);
            acc = __builtin_fmaf(av.y, wv.y, acc);
            acc = __builtin_fmaf(av.z, wv.z, acc);
            acc = __builtin_fmaf(av.w, wv.w, acc);
        }
        float v = __fadd_rn(acc, b1[j]);
        h1l[qloc][j] = v > 0.f ? v : __fmul_rn(0.2f, v);
    }
    __syncthreads();

    // ---- phase 5: np MLP2 (96 outs, K=192) -> A32 slot h+1 + sc LDS ----
    #pragma unroll 2
    for (int jj = 0; jj < 12; ++jj) {
        const int j = sub * 12 + jj;
        const float* wr = W2 + (size_t)j * 192;
        float acc = 0.f;
        #pragma unroll
        for (int k4 = 0; k4 < 48; ++k4) {
            float4 wv = *reinterpret_cast<const float4*>(wr + k4 * 4);
            float4 av = *reinterpret_cast<const float4*>(&h1l[qloc][k4 * 4]);
            acc = __builtin_fmaf(av.x, wv.x, acc);
            acc = __builtin_fmaf(av.y, wv.y, acc);
            acc = __builtin_fmaf(av.z, wv.z, acc);
            acc = __builtin_fmaf(av.w, wv.w, acc);
        }
        float v = __fadd_rn(acc, b2[j]);
        A32[(size_t)(p * Ll + (h + 1)) * Cc + j] = v;
        sc[qloc][j] = v;
    }
    __syncthreads();

    // ---- phase 6: np sq (pairwise-8 tree) + bf16 pack for slot h+1 ----
    if (sub == 0) {
        const float* x = &sc[qloc][0];
        float r[8];
        #pragma unroll
        for (int j = 0; j < 8; ++j) r[j] = __fmul_rn(x[j], x[j]);
        #pragma unroll
        for (int i = 8; i < 96; i += 8)
            #pragma unroll
            for (int j = 0; j < 8; ++j)
                r[j] = __fadd_rn(r[j], __fmul_rn(x[i + j], x[i + j]));
        float L = __fadd_rn(__fadd_rn(r[0], r[1]), __fadd_rn(r[2], r[3]));
        float R = __fadd_rn(__fadd_rn(r[4], r[5]), __fadd_rn(r[6], r[7]));
        sqnp[p] = __fadd_rn(L, R);
    }
    if (sub < 6) {   // 16 channels each -> 2 uint4 bf16 writes
        const float* x = &sc[qloc][sub * 16];
        uint4 o0, o1;
        o0.x = (unsigned)f2bf(x[0])  | ((unsigned)f2bf(x[1])  << 16);
        o0.y = (unsigned)f2bf(x[2])  | ((unsigned)f2bf(x[3])  << 16);
        o0.z = (unsigned)f2bf(x[4])  | ((unsigned)f2bf(x[5])  << 16);
        o0.w = (unsigned)f2bf(x[6])  | ((unsigned)f2bf(x[7])  << 16);
        o1.x = (unsigned)f2bf(x[8])  | ((unsigned)f2bf(x[9])  << 16);
        o1.y = (unsigned)f2bf(x[10]) | ((unsigned)f2bf(x[11]) << 16);
        o1.z = (unsigned)f2bf(x[12]) | ((unsigned)f2bf(x[13]) << 16);
        o1.w = (unsigned)f2bf(x[14]) | ((unsigned)f2bf(x[15]) << 16);
        uint4* d = reinterpret_cast<uint4*>(A16 + (size_t)p * 96 + sub * 16);
        d[0] = o0; d[1] = o1;
    }
}

// ---- swizzled fp32 tile staging for value-path gemm ----
__device__ inline void stage_row(const float* __restrict__ src, float* __restrict__ tile,
                                 int r, int q) {
    const int s = (r >> 2) & 7;
    #pragma unroll
    for (int m = 0; m < 6; ++m) {
        int g = q * 6 + m;
        float4 v = reinterpret_cast<const float4*>(src)[g];
        *reinterpret_cast<float4*>(&tile[r * KP + ((g ^ s) << 2)]) = v;
    }
}

// ---------------- fast fp32 GEMM (value path): out = Ain @ W^T + bias ----------------
template<int K>
__global__ __launch_bounds__(256) void gemm_kernel(const float* __restrict__ Ain,
                                                   const float* __restrict__ W,
                                                   const float* __restrict__ bias,
                                                   float* __restrict__ out,
                                                   int Nout, int out_stride) {
    __shared__ float a_t[64 * KP];
    __shared__ float w_t[64 * KP];
    const int row0 = blockIdx.x * 64;
    const int col0 = blockIdx.y * 64;
    const int tid  = threadIdx.x;
    const int tx   = tid & 15;
    const int ty   = tid >> 4;

    float acc[4][4] = {};
    for (int kt = 0; kt < K; kt += 96) {
        __syncthreads();
        {
            int r = tid >> 2, q = tid & 3;
            stage_row(Ain + (size_t)(row0 + r) * K + kt, a_t, r, q);
            if (col0 + r < Nout) {
                stage_row(W + (size_t)(col0 + r) * K + kt, w_t, r, q);
            } else {
                const int s = (r >> 2) & 7;
                #pragma unroll
                for (int m = 0; m < 6; ++m) {
                    int g = q * 6 + m;
                    *reinterpret_cast<float4*>(&w_t[r * KP + ((g ^ s) << 2)]) =
                        float4{0.f, 0.f, 0.f, 0.f};
                }
            }
        }
        __syncthreads();
        const int sa = ty & 7, sb = tx & 7;
        #pragma unroll 4
        for (int k4 = 0; k4 < 24; ++k4) {
            float4 av[4], bv[4];
            const int ga = (k4 ^ sa) << 2, gb = (k4 ^ sb) << 2;
            #pragma unroll
            for (int i = 0; i < 4; ++i)
                av[i] = *reinterpret_cast<const float4*>(&a_t[(ty * 4 + i) * KP + ga]);
            #pragma unroll
            for (int j = 0; j < 4; ++j)
                bv[j] = *reinterpret_cast<const float4*>(&w_t[(tx * 4 + j) * KP + gb]);
            #pragma unroll
            for (int i = 0; i < 4; ++i)
                #pragma unroll
                for (int j = 0; j < 4; ++j)
                    acc[i][j] += av[i].x * bv[j].x + av[i].y * bv[j].y +
                                 av[i].z * bv[j].z + av[i].w * bv[j].w;
        }
    }
    #pragma unroll
    for (int i = 0; i < 4; ++i) {
        int row = row0 + ty * 4 + i;
        #pragma unroll
        for (int j = 0; j < 4; ++j) {
            int col = col0 + tx * 4 + j;
            if (col < Nout)
                out[(size_t)row * out_stride + col] = acc[i][j] + bias[col];
        }
    }
}

// ---------------- per-(point, head) MHA; mean over 4 slots folded in ----------------
__global__ __launch_bounds__(64) void attn_kernel(const float* __restrict__ qkv,
                                                  float* __restrict__ mbuf) {
    int t  = blockIdx.x * 64 + threadIdx.x;
    int p  = t / 3;
    int hh = t - p * 3;
    const float* base = qkv + (size_t)p * 4 * 288;
    const float* qb = base + hh * 32;
    const float* kb = base + 96 + hh * 32;
    const float* vb = base + 192 + hh * 32;

    float sc[4][4] = {};
    #pragma unroll
    for (int d = 0; d < 32; d += 4) {
        float4 qv[4], kv[4];
        #pragma unroll
        for (int l = 0; l < 4; ++l) {
            qv[l] = *reinterpret_cast<const float4*>(qb + l * 288 + d);
            kv[l] = *reinterpret_cast<const float4*>(kb + l * 288 + d);
        }
        #pragma unroll
        for (int l = 0; l < 4; ++l)
            #pragma unroll
            for (int m = 0; m < 4; ++m)
                sc[l][m] += qv[l].x * kv[m].x + qv[l].y * kv[m].y +
                            qv[l].z * kv[m].z + qv[l].w * kv[m].w;
    }
    const float scale = 0.17677669529663687f;   // 1/sqrt(32)
    float am[4] = {0.f, 0.f, 0.f, 0.f};
    #pragma unroll
    for (int l = 0; l < 4; ++l) {
        float s0 = sc[l][0] * scale, s1 = sc[l][1] * scale;
        float s2 = sc[l][2] * scale, s3 = sc[l][3] * scale;
        float mx = fmaxf(fmaxf(s0, s1), fmaxf(s2, s3));
        float e0 = expf(s0 - mx), e1 = expf(s1 - mx);
        float e2 = expf(s2 - mx), e3 = expf(s3 - mx);
        float inv = 1.f / (e0 + e1 + e2 + e3);
        am[0] += e0 * inv; am[1] += e1 * inv; am[2] += e2 * inv; am[3] += e3 * inv;
    }
    am[0] *= 0.25f; am[1] *= 0.25f; am[2] *= 0.25f; am[3] *= 0.25f;
    #pragma unroll
    for (int d = 0; d < 32; d += 4) {
        float4 o = {0.f, 0.f, 0.f, 0.f};
        #pragma unroll
        for (int m = 0; m < 4; ++m) {
            float4 v = *reinterpret_cast<const float4*>(vb + m * 288 + d);
            o.x += am[m] * v.x; o.y += am[m] * v.y;
            o.z += am[m] * v.z; o.w += am[m] * v.w;
        }
        *reinterpret_cast<float4*>(mbuf + (size_t)p * 96 + hh * 32 + d) = o;
    }
}

}  // namespace

extern "C" void kernel_launch(void* const* d_in, const int* in_sizes, int n_in,
                              void* d_out, int out_size, void* d_ws, size_t ws_size,
                              hipStream_t stream) {
    const float* xyz = (const float*)d_in[0];
    const float* W1  = (const float*)d_in[1];
    const float* b1  = (const float*)d_in[2];
    const float* W2  = (const float*)d_in[3];
    const float* b2  = (const float*)d_in[4];
    const float* ipw = (const float*)d_in[5];
    const float* ipb = (const float*)d_in[6];
    const float* opw = (const float*)d_in[7];
    const float* opb = (const float*)d_in[8];

    char* ws = (char*)d_ws;
    float*  A32  = (float*)ws;                   // [65536][96]           25.2 MB
    float*  sqnp = (float*)(ws + 25165824);      // [16384]                64 KB
    int*    cand = (int*)  (ws + 25231360);      // [16384][96]           6.3 MB
    float*  qkvc = (float*)(ws + 50921472);      // [16384][288]         18.9 MB
    float*  mbuf = (float*)(ws + 69795840);      // [16384][96]           6.3 MB
    ushort* A16  = (ushort*)(ws + 76087296);     // [16384][96] bf16      3.1 MB

    sqcvt_kernel<<<256, 64, 0, stream>>>(xyz, A32, sqnp, A16);

    for (int h = 0; h < 3; ++h) {
        knn_mfma_kernel<<<dim3(NPTS / 64, CS), 256, 0, stream>>>(A16, sqnp, cand);
        hoptail_kernel<<<NPTS / 32, 256, 0, stream>>>(
            A32, sqnp, cand,
            W1 + (size_t)h * 192 * 96, b1 + h * 192,
            W2 + (size_t)h * 96 * 192, b2 + h * 96, A16, h);
    }

    // MHA: merged single-launch path if workspace allows
    const size_t need = 100728832ull + 6291456ull;   // qkvc4 end + mbuf4
    if (ws_size >= need) {
        float* qkvc4 = (float*)(ws + 25231360);      // [65536][288]  75.5 MB
        float* mbuf4 = (float*)(ws + 100728832);     // [16384][96]    6.3 MB
        gemm_kernel<96><<<dim3(65536 / 64, 5), 256, 0, stream>>>(
            A32, ipw, ipb, qkvc4, 288, 288);
        attn_kernel<<<NPTS * 3 / 64, 64, 0, stream>>>(qkvc4, mbuf4);
        gemm_kernel<96><<<dim3(NPTS / 64, 2), 256, 0, stream>>>(
            mbuf4, opw, opb, (float*)d_out, 96, 96);
    } else {
        for (int b = 0; b < Bb; ++b) {
            gemm_kernel<96><<<dim3(16384 / 64, 5), 256, 0, stream>>>(
                A32 + (size_t)b * 4096 * Ll * Cc, ipw, ipb, qkvc, 288, 288);
            attn_kernel<<<192, 64, 0, stream>>>(qkvc, mbuf + (size_t)b * 4096 * 96);
        }
        gemm_kernel<96><<<dim3(NPTS / 64, 2), 256, 0, stream>>>(
            mbuf, opw, opb, (float*)d_out, 96, 96);
    }
}

// Round 16
// 1407.936 us; speedup vs baseline: 1.4236x; 1.4236x over previous
//
#include <hip/hip_runtime.h>
#include <cfloat>

namespace {

constexpr int Bb    = 4;
constexpr int Nn    = 4096;
constexpr int Cc    = 96;
constexpr int Ll    = 4;           // hops+1 slots
constexpr int NPTS  = Bb * Nn;     // 16384
constexpr int KP    = 100;         // padded LDS row stride (floats) for fp32 gemm
constexpr int CS    = 2;           // column splits of the db dimension
constexpr int TK    = 12;          // per-lane candidates
constexpr int NCROW = CS * 4 * TK; // 96 candidates per row
constexpr int LP    = 104;         // bf16 LDS row pitch (208 B)
constexpr int NSEL  = 24;          // np-rescored survivors of the fast-key merge

typedef __attribute__((ext_vector_type(8))) short bf16x8;
typedef __attribute__((ext_vector_type(4))) float f32x4;

// RNE fp32 -> bf16 (candidate ranking only)
__device__ inline ushort f2bf(float x) {
    unsigned u = __float_as_uint(x);
    return (ushort)((u + 0x7FFF + ((u >> 16) & 1)) >> 16);
}

// lexicographic (value asc, index asc) sorted-insert into top-T
template<int T>
__device__ inline void lexins(float v, int vi, float (&bd)[T], int (&bi)[T]) {
    if (v < bd[T - 1] || (v == bd[T - 1] && vi < bi[T - 1])) {
        #pragma unroll
        for (int t = 0; t < T; ++t) {
            if (v < bd[t] || (v == bd[t] && vi < bi[t])) {
                float tv = bd[t]; bd[t] = v;  v  = tv;
                int   ti = bi[t]; bi[t] = vi; vi = ti;
            }
        }
    }
}

// ---- fused: (optional xyz->A32 slot0 copy) + np-mimic sq (pairwise-8) + bf16 cvt ----
template<bool COPY>
__global__ __launch_bounds__(64) void sqcvt_kernel(const float* __restrict__ src0,
                                                   float* __restrict__ A32,
                                                   float* __restrict__ sqnp,
                                                   ushort* __restrict__ A16, int h) {
    const int p = blockIdx.x * 64 + threadIdx.x;
    const float4* xs = reinterpret_cast<const float4*>(
        COPY ? src0 + (size_t)p * Cc : src0 + (size_t)(p * Ll + h) * Cc);
    float4 x[24];
    #pragma unroll
    for (int i = 0; i < 24; ++i) x[i] = xs[i];
    if (COPY) {
        float4* d = reinterpret_cast<float4*>(A32 + (size_t)p * Ll * Cc);
        #pragma unroll
        for (int i = 0; i < 24; ++i) d[i] = x[i];
    }
    // numpy pairwise-8 tree over fl(x*x)
    float r[8];
    r[0] = __fmul_rn(x[0].x, x[0].x); r[1] = __fmul_rn(x[0].y, x[0].y);
    r[2] = __fmul_rn(x[0].z, x[0].z); r[3] = __fmul_rn(x[0].w, x[0].w);
    r[4] = __fmul_rn(x[1].x, x[1].x); r[5] = __fmul_rn(x[1].y, x[1].y);
    r[6] = __fmul_rn(x[1].z, x[1].z); r[7] = __fmul_rn(x[1].w, x[1].w);
    #pragma unroll
    for (int g = 1; g < 12; ++g) {
        float4 va = x[2 * g], vb = x[2 * g + 1];
        r[0] = __fadd_rn(r[0], __fmul_rn(va.x, va.x));
        r[1] = __fadd_rn(r[1], __fmul_rn(va.y, va.y));
        r[2] = __fadd_rn(r[2], __fmul_rn(va.z, va.z));
        r[3] = __fadd_rn(r[3], __fmul_rn(va.w, va.w));
        r[4] = __fadd_rn(r[4], __fmul_rn(vb.x, vb.x));
        r[5] = __fadd_rn(r[5], __fmul_rn(vb.y, vb.y));
        r[6] = __fadd_rn(r[6], __fmul_rn(vb.z, vb.z));
        r[7] = __fadd_rn(r[7], __fmul_rn(vb.w, vb.w));
    }
    float L = __fadd_rn(__fadd_rn(r[0], r[1]), __fadd_rn(r[2], r[3]));
    float R = __fadd_rn(__fadd_rn(r[4], r[5]), __fadd_rn(r[6], r[7]));
    sqnp[p] = __fadd_rn(L, R);
    #pragma unroll
    for (int j = 0; j < 12; ++j) {
        float4 v0 = x[2 * j], v1 = x[2 * j + 1];
        uint4 o;
        o.x = (unsigned)f2bf(v0.x) | ((unsigned)f2bf(v0.y) << 16);
        o.y = (unsigned)f2bf(v0.z) | ((unsigned)f2bf(v0.w) << 16);
        o.z = (unsigned)f2bf(v1.x) | ((unsigned)f2bf(v1.y) << 16);
        o.w = (unsigned)f2bf(v1.z) | ((unsigned)f2bf(v1.w) << 16);
        *reinterpret_cast<uint4*>(A16 + (size_t)p * 96 + j * 8) = o;
    }
}

// ---- MFMA candidate pass (R11-proven): chunk=64, LDS double-buffer staging ----
// Also emits the fast keys (s = dot - sq/2, DESC order per stream) so the
// rescore stage can merge-filter WITHOUT gathering feature rows.
__global__ __launch_bounds__(256) void knn_mfma_kernel(const ushort* __restrict__ A16,
                                                       const float* __restrict__ sqnp,
                                                       int* __restrict__ cand,
                                                       float* __restrict__ fkey) {
    __shared__ ushort qt[64 * LP];
    __shared__ ushort dbt[2][64 * LP];
    __shared__ float  sqf[2][64];
    __shared__ float  klds[256 * 20];

    const int q0    = blockIdx.x * 64;
    const int cs    = blockIdx.y;
    const int pbase = (q0 >> 12) << 12;
    const int col0  = cs * (Nn / CS);
    const int tid   = threadIdx.x;
    const int w     = tid >> 6;
    const int l     = tid & 63;
    constexpr int NCH = (Nn / CS) / 64;

    {
        int r = tid >> 2, q = tid & 3;
        const uint4* s = reinterpret_cast<const uint4*>(A16 + (size_t)(q0 + r) * 96 + q * 24);
        uint4* d = reinterpret_cast<uint4*>(qt + r * LP + q * 24);
        d[0] = s[0]; d[1] = s[1]; d[2] = s[2];
        const uint4* s2 = reinterpret_cast<const uint4*>(
            A16 + (size_t)(pbase + col0 + r) * 96 + q * 24);
        uint4* d2 = reinterpret_cast<uint4*>(dbt[0] + r * LP + q * 24);
        d2[0] = s2[0]; d2[1] = s2[1]; d2[2] = s2[2];
    }
    if (tid < 64) sqf[0][tid] = -0.5f * sqnp[pbase + col0 + tid];
    __syncthreads();

    const int qrow = w * 16 + (l & 15);
    const int koff = (l >> 4) * 8;
    const int lb4  = (l >> 4) * 4;
    bf16x8 bq[3];
    #pragma unroll
    for (int s = 0; s < 3; ++s)
        bq[s] = *reinterpret_cast<const bf16x8*>(qt + qrow * LP + koff + 32 * s);

    float bd[TK]; int bi[TK];
    #pragma unroll
    for (int t = 0; t < TK; ++t) { bd[t] = -FLT_MAX; bi[t] = 0x7fffffff; }
    float kd = -FLT_MAX;

    for (int c = 0; c < NCH; ++c) {
        const int buf = c & 1;
        if (c + 1 < NCH) {
            int r = tid >> 2, q = tid & 3;
            const uint4* s = reinterpret_cast<const uint4*>(
                A16 + (size_t)(pbase + col0 + (c + 1) * 64 + r) * 96 + q * 24);
            uint4* d = reinterpret_cast<uint4*>(dbt[buf ^ 1] + r * LP + q * 24);
            d[0] = s[0]; d[1] = s[1]; d[2] = s[2];
            if (tid < 64) sqf[buf ^ 1][tid] = -0.5f * sqnp[pbase + col0 + (c + 1) * 64 + tid];
        }

        f32x4 acc[4];
        #pragma unroll
        for (int sub = 0; sub < 4; ++sub) {
            acc[sub] = *reinterpret_cast<const f32x4*>(&sqf[buf][sub * 16 + lb4]);
            #pragma unroll
            for (int s = 0; s < 3; ++s) {
                bf16x8 a = *reinterpret_cast<const bf16x8*>(
                    dbt[buf] + (sub * 16 + (l & 15)) * LP + koff + 32 * s);
                acc[sub] = __builtin_amdgcn_mfma_f32_16x16x32_bf16(a, bq[s], acc[sub], 0, 0, 0);
            }
        }

        unsigned mask = 0;
        #pragma unroll
        for (int sub = 0; sub < 4; ++sub) {
            float m = fmaxf(fmaxf(acc[sub][0], acc[sub][1]),
                            fmaxf(acc[sub][2], acc[sub][3]));
            if (m > kd) {
                *reinterpret_cast<f32x4*>(&klds[tid * 20 + sub * 4]) = acc[sub];
                unsigned mb = (acc[sub][0] > kd ? 1u : 0u) |
                              (acc[sub][1] > kd ? 2u : 0u) |
                              (acc[sub][2] > kd ? 4u : 0u) |
                              (acc[sub][3] > kd ? 8u : 0u);
                mask |= mb << (sub * 4);
            }
        }
        const int cbase = col0 + c * 64 + lb4;
        while (mask) {
            int s = __builtin_ctz(mask); mask &= mask - 1;
            float v = klds[tid * 20 + s];
            int vi = cbase + ((s >> 2) << 4) + (s & 3);
            if (v > kd) {
                #pragma unroll
                for (int t = 0; t < TK; ++t) {
                    if (v > bd[t] || (v == bd[t] && vi < bi[t])) {
                        float tv = bd[t]; bd[t] = v;  v  = tv;
                        int   ti = bi[t]; bi[t] = vi; vi = ti;
                    }
                }
                kd = bd[TK - 1];
            }
        }
        __syncthreads();
    }

    const int qg = q0 + qrow;
    const size_t obase = (size_t)qg * NCROW + (cs * 4 + (l >> 4)) * TK;
    #pragma unroll
    for (int t = 0; t < TK; ++t) {
        cand[obase + t] = bi[t];
        fkey[obase + t] = bd[t];
    }
}

// ---- np-exact rescore with gather-free fast-key prefilter + np mean ----
// Phase 0: load 96 (fkey, idx) pairs (768 B/query — no feature gather).
// Phase 0b: exact 8-way merge of the sorted streams -> fast-key top-24.
// Phase 1: gather + np-exact rescore ONLY the 24 survivors (9.2 KB/query).
// Phase 2: stable top-8 by (d2, idx). Phase 3: np-mimic mean.
// block 256 = 32 queries x 8 subs; grid NPTS/32.
__global__ __launch_bounds__(256) void rescore_mean_kernel(const float* __restrict__ A32,
                                                           const float* __restrict__ sqnp,
                                                           const int* __restrict__ cand,
                                                           const float* __restrict__ fkey,
                                                           float* __restrict__ nb, int h) {
    __shared__ float kly[32][100];   // fast keys (8 sorted streams of 12)
    __shared__ int   cly[32][100];   // candidate indices
    __shared__ int   m24[32][NSEL];  // merged fast-key top-24 indices
    __shared__ float s24[32][NSEL];  // np-exact d2 of survivors
    __shared__ int   sidx[32][8];
    const int tid  = threadIdx.x;
    const int qloc = tid >> 3, sub = tid & 7;
    const int p    = blockIdx.x * 32 + qloc;
    const int base = (p >> 12) << 12;

    // ---- phase 0: stream pairs into LDS ----
    {
        const float4* fs = reinterpret_cast<const float4*>(fkey + (size_t)p * NCROW + sub * 12);
        const int4*   is = reinterpret_cast<const int4*>(cand + (size_t)p * NCROW + sub * 12);
        float4 k0 = fs[0], k1 = fs[1], k2 = fs[2];
        int4   i0 = is[0], i1 = is[1], i2 = is[2];
        *reinterpret_cast<float4*>(&kly[qloc][sub * 12])     = k0;
        *reinterpret_cast<float4*>(&kly[qloc][sub * 12 + 4]) = k1;
        *reinterpret_cast<float4*>(&kly[qloc][sub * 12 + 8]) = k2;
        *reinterpret_cast<int4*>(&cly[qloc][sub * 12])       = i0;
        *reinterpret_cast<int4*>(&cly[qloc][sub * 12 + 4])   = i1;
        *reinterpret_cast<int4*>(&cly[qloc][sub * 12 + 8])   = i2;
    }
    __syncthreads();

    // ---- phase 0b: exact top-24 by (fast key DESC, idx ASC) — 8-way list merge.
    // Streams are pre-sorted by knn's insertion. Heads packed as 8x4-bit nibbles.
    if (sub == 0) {
        unsigned hp = 0;
        #pragma unroll 1
        for (int t = 0; t < NSEL; ++t) {
            float bk = -FLT_MAX; int bs = 0, bidx = 0x7fffffff;
            #pragma unroll
            for (int s = 0; s < 8; ++s) {
                int hs = (hp >> (4 * s)) & 15;
                if (hs < 12) {
                    float k = kly[qloc][s * 12 + hs];
                    int   i = cly[qloc][s * 12 + hs];
                    if (k > bk || (k == bk && i < bidx)) { bk = k; bs = s; bidx = i; }
                }
            }
            m24[qloc][t] = bidx;
            hp += 1u << (4 * bs);
        }
    }
    __syncthreads();

    // ---- phase 1: np-exact rescore of the 24 survivors (3 per sub) ----
    {
        float4 xnr[24];
        const float4* xs = reinterpret_cast<const float4*>(A32 + (size_t)(p * Ll + h) * Cc);
        #pragma unroll
        for (int i = 0; i < 24; ++i) xnr[i] = xs[i];
        const float sqn = sqnp[p];
        #pragma unroll
        for (int c = 0; c < NSEL / 8; ++c) {
            int m = m24[qloc][sub * (NSEL / 8) + c];
            const float4* xm = reinterpret_cast<const float4*>(
                A32 + (size_t)((base + m) * Ll + h) * Cc);
            // np einsum dot: SSE SOP — 4-lane mul+add accumulators, hadd combine
            float l0 = 0.f, l1 = 0.f, l2 = 0.f, l3 = 0.f;
            #pragma unroll
            for (int t = 0; t < 24; ++t) {
                float4 a = xnr[t], b = xm[t];
                l0 = __fadd_rn(l0, __fmul_rn(a.x, b.x));
                l1 = __fadd_rn(l1, __fmul_rn(a.y, b.y));
                l2 = __fadd_rn(l2, __fmul_rn(a.z, b.z));
                l3 = __fadd_rn(l3, __fmul_rn(a.w, b.w));
            }
            float dot = __fadd_rn(__fadd_rn(l0, l1), __fadd_rn(l2, l3));
            // np: d2 = fl(fl(sq_n + sq_m) - fl(2*dot))
            s24[qloc][sub * (NSEL / 8) + c] =
                __fsub_rn(__fadd_rn(sqn, sqnp[base + m]), __fmul_rn(2.0f, dot));
        }
    }
    __syncthreads();

    // ---- phase 2: stable top-8 by (d2, idx) — lax.top_k tie semantics ----
    if (sub == 0) {
        float sd[8]; int si[8];
        #pragma unroll
        for (int t = 0; t < 8; ++t) { sd[t] = FLT_MAX; si[t] = 0x7fffffff; }
        #pragma unroll 1
        for (int c = 0; c < NSEL; ++c) lexins<8>(s24[qloc][c], m24[qloc][c], sd, si);
        #pragma unroll
        for (int t = 0; t < 8; ++t) sidx[qloc][t] = si[t];
    }
    __syncthreads();

    // ---- phase 3: np-mimic mean (pairwise-8 tree, x0.125) ----
    {
        float4 rv[8][3];
        #pragma unroll
        for (int k = 0; k < 8; ++k) {
            const float4* rs = reinterpret_cast<const float4*>(
                A32 + (size_t)((base + sidx[qloc][k]) * Ll + h) * Cc + sub * 12);
            rv[k][0] = rs[0]; rv[k][1] = rs[1]; rv[k][2] = rs[2];
        }
        float4* dst = reinterpret_cast<float4*>(nb + (size_t)p * Cc + sub * 12);
        #pragma unroll
        for (int g = 0; g < 3; ++g) {
            float4 o;
            #define NPMEAN(comp) { \
                float L_ = __fadd_rn(__fadd_rn(rv[0][g].comp, rv[1][g].comp), \
                                     __fadd_rn(rv[2][g].comp, rv[3][g].comp)); \
                float R_ = __fadd_rn(__fadd_rn(rv[4][g].comp, rv[5][g].comp), \
                                     __fadd_rn(rv[6][g].comp, rv[7][g].comp)); \
                o.comp = __fmul_rn(__fadd_rn(L_, R_), 0.125f); }
            NPMEAN(x) NPMEAN(y) NPMEAN(z) NPMEAN(w)
            #undef NPMEAN
            dst[g] = o;
        }
    }
}

// ---- np-mimic MLP GEMM: out = act(A @ W^T + bias); BLAS-style sequential-k FMA.
// W tile staged in LDS ONCE per 16 rows (4 rows/thread). FP chain per (i,j)
// IDENTICAL to the scalar version. grid (ceil(N/64), M/16), block (64,4).
template<int K, bool LEAKY>
__global__ __launch_bounds__(256) void npgemm_kernel(const float* __restrict__ A,
                                                     const float* __restrict__ W,
                                                     const float* __restrict__ bias,
                                                     float* __restrict__ out,
                                                     int N, int ostride) {
    constexpr int PW = (K == 96) ? 100 : 196;   // padded row stride (mult of 4)
    __shared__ float w_t[64 * PW];
    const int tx = threadIdx.x, ty = threadIdx.y;
    const int col0 = blockIdx.x * 64;
    const int j = col0 + tx;
    const int i0 = blockIdx.y * 16 + ty * 4;    // 4 consecutive rows per thread
    {
        int tid = ty * 64 + tx;
        int r = tid >> 2, q = tid & 3;
        constexpr int G = K / 16;               // float4 groups per quarter-thread
        float4* dst = reinterpret_cast<float4*>(&w_t[r * PW]) + q * G;
        if (col0 + r < N) {
            const float4* src = reinterpret_cast<const float4*>(
                W + (size_t)(col0 + r) * K) + q * G;
            #pragma unroll
            for (int m = 0; m < G; ++m) dst[m] = src[m];
        } else {
            #pragma unroll
            for (int m = 0; m < G; ++m) dst[m] = float4{0.f, 0.f, 0.f, 0.f};
        }
    }
    __syncthreads();
    if (j < N) {
        #pragma unroll
        for (int rr = 0; rr < 4; ++rr) {
            const float* a = A + (size_t)(i0 + rr) * K;   // wave-uniform row
            float acc = 0.f;
            #pragma unroll
            for (int k4 = 0; k4 < K / 4; ++k4) {
                float4 wv = *reinterpret_cast<const float4*>(&w_t[tx * PW + k4 * 4]);
                float4 av = *reinterpret_cast<const float4*>(a + k4 * 4);
                acc = __builtin_fmaf(av.x, wv.x, acc);
                acc = __builtin_fmaf(av.y, wv.y, acc);
                acc = __builtin_fmaf(av.z, wv.z, acc);
                acc = __builtin_fmaf(av.w, wv.w, acc);
            }
            float v = __fadd_rn(acc, bias[j]);
            if (LEAKY) v = v > 0.f ? v : __fmul_rn(0.2f, v);
            out[(size_t)(i0 + rr) * ostride + j] = v;
        }
    }
}

// ---- swizzled fp32 tile staging for value-path gemm ----
__device__ inline void stage_row(const float* __restrict__ src, float* __restrict__ tile,
                                 int r, int q) {
    const int s = (r >> 2) & 7;
    #pragma unroll
    for (int m = 0; m < 6; ++m) {
        int g = q * 6 + m;
        float4 v = reinterpret_cast<const float4*>(src)[g];
        *reinterpret_cast<float4*>(&tile[r * KP + ((g ^ s) << 2)]) = v;
    }
}

// ---------------- fast fp32 GEMM (value path): out = Ain @ W^T + bias ----------------
template<int K>
__global__ __launch_bounds__(256) void gemm_kernel(const float* __restrict__ Ain,
                                                   const float* __restrict__ W,
                                                   const float* __restrict__ bias,
                                                   float* __restrict__ out,
                                                   int Nout, int out_stride) {
    __shared__ float a_t[64 * KP];
    __shared__ float w_t[64 * KP];
    const int row0 = blockIdx.x * 64;
    const int col0 = blockIdx.y * 64;
    const int tid  = threadIdx.x;
    const int tx   = tid & 15;
    const int ty   = tid >> 4;

    float acc[4][4] = {};
    for (int kt = 0; kt < K; kt += 96) {
        __syncthreads();
        {
            int r = tid >> 2, q = tid & 3;
            stage_row(Ain + (size_t)(row0 + r) * K + kt, a_t, r, q);
            if (col0 + r < Nout) {
                stage_row(W + (size_t)(col0 + r) * K + kt, w_t, r, q);
            } else {
                const int s = (r >> 2) & 7;
                #pragma unroll
                for (int m = 0; m < 6; ++m) {
                    int g = q * 6 + m;
                    *reinterpret_cast<float4*>(&w_t[r * KP + ((g ^ s) << 2)]) =
                        float4{0.f, 0.f, 0.f, 0.f};
                }
            }
        }
        __syncthreads();
        const int sa = ty & 7, sb = tx & 7;
        #pragma unroll 4
        for (int k4 = 0; k4 < 24; ++k4) {
            float4 av[4], bv[4];
            const int ga = (k4 ^ sa) << 2, gb = (k4 ^ sb) << 2;
            #pragma unroll
            for (int i = 0; i < 4; ++i)
                av[i] = *reinterpret_cast<const float4*>(&a_t[(ty * 4 + i) * KP + ga]);
            #pragma unroll
            for (int j = 0; j < 4; ++j)
                bv[j] = *reinterpret_cast<const float4*>(&w_t[(tx * 4 + j) * KP + gb]);
            #pragma unroll
            for (int i = 0; i < 4; ++i)
                #pragma unroll
                for (int j = 0; j < 4; ++j)
                    acc[i][j] += av[i].x * bv[j].x + av[i].y * bv[j].y +
                                 av[i].z * bv[j].z + av[i].w * bv[j].w;
        }
    }
    #pragma unroll
    for (int i = 0; i < 4; ++i) {
        int row = row0 + ty * 4 + i;
        #pragma unroll
        for (int j = 0; j < 4; ++j) {
            int col = col0 + tx * 4 + j;
            if (col < Nout)
                out[(size_t)row * out_stride + col] = acc[i][j] + bias[col];
        }
    }
}

// ---------------- per-(point, head) MHA; mean over 4 slots folded in ----------------
__global__ __launch_bounds__(64) void attn_kernel(const float* __restrict__ qkv,
                                                  float* __restrict__ mbuf) {
    int t  = blockIdx.x * 64 + threadIdx.x;
    int p  = t / 3;
    int hh = t - p * 3;
    const float* base = qkv + (size_t)p * 4 * 288;
    const float* qb = base + hh * 32;
    const float* kb = base + 96 + hh * 32;
    const float* vb = base + 192 + hh * 32;

    float sc[4][4] = {};
    #pragma unroll
    for (int d = 0; d < 32; d += 4) {
        float4 qv[4], kv[4];
        #pragma unroll
        for (int l = 0; l < 4; ++l) {
            qv[l] = *reinterpret_cast<const float4*>(qb + l * 288 + d);
            kv[l] = *reinterpret_cast<const float4*>(kb + l * 288 + d);
        }
        #pragma unroll
        for (int l = 0; l < 4; ++l)
            #pragma unroll
            for (int m = 0; m < 4; ++m)
                sc[l][m] += qv[l].x * kv[m].x + qv[l].y * kv[m].y +
                            qv[l].z * kv[m].z + qv[l].w * kv[m].w;
    }
    const float scale = 0.17677669529663687f;   // 1/sqrt(32)
    float am[4] = {0.f, 0.f, 0.f, 0.f};
    #pragma unroll
    for (int l = 0; l < 4; ++l) {
        float s0 = sc[l][0] * scale, s1 = sc[l][1] * scale;
        float s2 = sc[l][2] * scale, s3 = sc[l][3] * scale;
        float mx = fmaxf(fmaxf(s0, s1), fmaxf(s2, s3));
        float e0 = expf(s0 - mx), e1 = expf(s1 - mx);
        float e2 = expf(s2 - mx), e3 = expf(s3 - mx);
        float inv = 1.f / (e0 + e1 + e2 + e3);
        am[0] += e0 * inv; am[1] += e1 * inv; am[2] += e2 * inv; am[3] += e3 * inv;
    }
    am[0] *= 0.25f; am[1] *= 0.25f; am[2] *= 0.25f; am[3] *= 0.25f;
    #pragma unroll
    for (int d = 0; d < 32; d += 4) {
        float4 o = {0.f, 0.f, 0.f, 0.f};
        #pragma unroll
        for (int m = 0; m < 4; ++m) {
            float4 v = *reinterpret_cast<const float4*>(vb + m * 288 + d);
            o.x += am[m] * v.x; o.y += am[m] * v.y;
            o.z += am[m] * v.z; o.w += am[m] * v.w;
        }
        *reinterpret_cast<float4*>(mbuf + (size_t)p * 96 + hh * 32 + d) = o;
    }
}

}  // namespace

extern "C" void kernel_launch(void* const* d_in, const int* in_sizes, int n_in,
                              void* d_out, int out_size, void* d_ws, size_t ws_size,
                              hipStream_t stream) {
    const float* xyz = (const float*)d_in[0];
    const float* W1  = (const float*)d_in[1];
    const float* b1  = (const float*)d_in[2];
    const float* W2  = (const float*)d_in[3];
    const float* b2  = (const float*)d_in[4];
    const float* ipw = (const float*)d_in[5];
    const float* ipb = (const float*)d_in[6];
    const float* opw = (const float*)d_in[7];
    const float* opb = (const float*)d_in[8];

    char* ws = (char*)d_ws;
    float*  A32  = (float*)ws;                   // [65536][96]           25.2 MB
    float*  sqnp = (float*)(ws + 25165824);      // [16384]                64 KB
    int*    cand = (int*)  (ws + 25231360);      // [16384][96]           6.3 MB
    float*  nb   = (float*)(ws + 32047104);      // [16384][96]           6.3 MB
    float*  h1   = (float*)(ws + 38338560);      // [16384][192]         12.6 MB
    float*  qkvc = (float*)(ws + 50921472);      // [16384][288]         18.9 MB
    float*  mbuf = (float*)(ws + 69795840);      // [16384][96]           6.3 MB
    ushort* A16  = (ushort*)(ws + 76087296);     // [16384][96] bf16      3.1 MB
    float*  fkey = (float*)(ws + 79233024);      // [16384][96]           6.3 MB
    // hop-phase footprint ~85.5 MB

    for (int h = 0; h < 3; ++h) {
        if (h == 0)
            sqcvt_kernel<true><<<256, 64, 0, stream>>>(xyz, A32, sqnp, A16, 0);
        else
            sqcvt_kernel<false><<<256, 64, 0, stream>>>(A32, A32, sqnp, A16, h);
        knn_mfma_kernel<<<dim3(NPTS / 64, CS), 256, 0, stream>>>(A16, sqnp, cand, fkey);
        rescore_mean_kernel<<<NPTS / 32, 256, 0, stream>>>(A32, sqnp, cand, fkey, nb, h);
        npgemm_kernel<96, true><<<dim3(3, NPTS / 16), dim3(64, 4), 0, stream>>>(
            nb, W1 + (size_t)h * 192 * 96, b1 + h * 192, h1, 192, 192);
        npgemm_kernel<192, false><<<dim3(2, NPTS / 16), dim3(64, 4), 0, stream>>>(
            h1, W2 + (size_t)h * 96 * 192, b2 + h * 96, A32 + (h + 1) * 96, 96, Ll * Cc);
    }

    // MHA: merged single-launch path if workspace allows (hop buffers dead)
    const size_t need = 100728832ull + 6291456ull;   // qkvc4 end + mbuf4
    if (ws_size >= need) {
        float* qkvc4 = (float*)(ws + 25231360);      // [65536][288]  75.5 MB
        float* mbuf4 = (float*)(ws + 100728832);     // [16384][96]    6.3 MB
        gemm_kernel<96><<<dim3(65536 / 64, 5), 256, 0, stream>>>(
            A32, ipw, ipb, qkvc4, 288, 288);
        attn_kernel<<<NPTS * 3 / 64, 64, 0, stream>>>(qkvc4, mbuf4);
        gemm_kernel<96><<<dim3(NPTS / 64, 2), 256, 0, stream>>>(
            mbuf4, opw, opb, (float*)d_out, 96, 96);
    } else {
        for (int b = 0; b < Bb; ++b) {
            gemm_kernel<96><<<dim3(16384 / 64, 5), 256, 0, stream>>>(
                A32 + (size_t)b * 4096 * Ll * Cc, ipw, ipb, qkvc, 288, 288);
            attn_kernel<<<192, 64, 0, stream>>>(qkvc, mbuf + (size_t)b * 4096 * 96);
        }
        gemm_kernel<96><<<dim3(NPTS / 64, 2), 256, 0, stream>>>(
            mbuf, opw, opb, (float*)d_out, 96, 96);
    }
}

// Round 17
// 952.640 us; speedup vs baseline: 2.1040x; 1.4779x over previous
//
#include <hip/hip_runtime.h>
#include <cfloat>

namespace {

constexpr int Bb    = 4;
constexpr int Nn    = 4096;
constexpr int Cc    = 96;
constexpr int Ll    = 4;           // hops+1 slots
constexpr int NPTS  = Bb * Nn;     // 16384
constexpr int KP    = 100;         // padded LDS row stride (floats) for fp32 gemm
constexpr int CS    = 2;           // column splits of the db dimension
constexpr int TK    = 12;          // per-lane candidates
constexpr int NCROW = CS * 4 * TK; // 96 candidates per row
constexpr int LP    = 104;         // bf16 LDS row pitch (208 B)
constexpr int NSEL  = 24;          // np-rescored survivors of the fast-key merge

typedef __attribute__((ext_vector_type(8))) short bf16x8;
typedef __attribute__((ext_vector_type(4))) float f32x4;

// RNE fp32 -> bf16 (candidate ranking only)
__device__ inline ushort f2bf(float x) {
    unsigned u = __float_as_uint(x);
    return (ushort)((u + 0x7FFF + ((u >> 16) & 1)) >> 16);
}

// lexicographic (value asc, index asc) sorted-insert into top-T
template<int T>
__device__ inline void lexins(float v, int vi, float (&bd)[T], int (&bi)[T]) {
    if (v < bd[T - 1] || (v == bd[T - 1] && vi < bi[T - 1])) {
        #pragma unroll
        for (int t = 0; t < T; ++t) {
            if (v < bd[t] || (v == bd[t] && vi < bi[t])) {
                float tv = bd[t]; bd[t] = v;  v  = tv;
                int   ti = bi[t]; bi[t] = vi; vi = ti;
            }
        }
    }
}

// ---- fused: (optional xyz->A32 slot0 copy) + np-mimic sq (pairwise-8) + bf16 cvt ----
template<bool COPY>
__global__ __launch_bounds__(64) void sqcvt_kernel(const float* __restrict__ src0,
                                                   float* __restrict__ A32,
                                                   float* __restrict__ sqnp,
                                                   ushort* __restrict__ A16, int h) {
    const int p = blockIdx.x * 64 + threadIdx.x;
    const float4* xs = reinterpret_cast<const float4*>(
        COPY ? src0 + (size_t)p * Cc : src0 + (size_t)(p * Ll + h) * Cc);
    float4 x[24];
    #pragma unroll
    for (int i = 0; i < 24; ++i) x[i] = xs[i];
    if (COPY) {
        float4* d = reinterpret_cast<float4*>(A32 + (size_t)p * Ll * Cc);
        #pragma unroll
        for (int i = 0; i < 24; ++i) d[i] = x[i];
    }
    // numpy pairwise-8 tree over fl(x*x)
    float r[8];
    r[0] = __fmul_rn(x[0].x, x[0].x); r[1] = __fmul_rn(x[0].y, x[0].y);
    r[2] = __fmul_rn(x[0].z, x[0].z); r[3] = __fmul_rn(x[0].w, x[0].w);
    r[4] = __fmul_rn(x[1].x, x[1].x); r[5] = __fmul_rn(x[1].y, x[1].y);
    r[6] = __fmul_rn(x[1].z, x[1].z); r[7] = __fmul_rn(x[1].w, x[1].w);
    #pragma unroll
    for (int g = 1; g < 12; ++g) {
        float4 va = x[2 * g], vb = x[2 * g + 1];
        r[0] = __fadd_rn(r[0], __fmul_rn(va.x, va.x));
        r[1] = __fadd_rn(r[1], __fmul_rn(va.y, va.y));
        r[2] = __fadd_rn(r[2], __fmul_rn(va.z, va.z));
        r[3] = __fadd_rn(r[3], __fmul_rn(va.w, va.w));
        r[4] = __fadd_rn(r[4], __fmul_rn(vb.x, vb.x));
        r[5] = __fadd_rn(r[5], __fmul_rn(vb.y, vb.y));
        r[6] = __fadd_rn(r[6], __fmul_rn(vb.z, vb.z));
        r[7] = __fadd_rn(r[7], __fmul_rn(vb.w, vb.w));
    }
    float L = __fadd_rn(__fadd_rn(r[0], r[1]), __fadd_rn(r[2], r[3]));
    float R = __fadd_rn(__fadd_rn(r[4], r[5]), __fadd_rn(r[6], r[7]));
    sqnp[p] = __fadd_rn(L, R);
    #pragma unroll
    for (int j = 0; j < 12; ++j) {
        float4 v0 = x[2 * j], v1 = x[2 * j + 1];
        uint4 o;
        o.x = (unsigned)f2bf(v0.x) | ((unsigned)f2bf(v0.y) << 16);
        o.y = (unsigned)f2bf(v0.z) | ((unsigned)f2bf(v0.w) << 16);
        o.z = (unsigned)f2bf(v1.x) | ((unsigned)f2bf(v1.y) << 16);
        o.w = (unsigned)f2bf(v1.z) | ((unsigned)f2bf(v1.w) << 16);
        *reinterpret_cast<uint4*>(A16 + (size_t)p * 96 + j * 8) = o;
    }
}

// ---- MFMA candidate pass: chunk=64 double-buffer + PACKED-KEY scan ----
// acc init = -sq/2 -> accumulator holds s = dot - sq/2 (d2 asc == s DESC).
// Key packing: (ordered_uint(v) & ~511) | (511 - stream_pos). One u32 carries
// (value DESC, pos ASC); the insert chain is a max/min bubble (2 VALU/step vs
// ~7 for the two-field chain). 9 truncated mantissa bits only perturb candidate
// ranking within ties far below bf16 noise — candidate set stays a
// deterministic superset; np-exact selection downstream is unchanged.
// grid (NPTS/64, CS), block 256.
__global__ __launch_bounds__(256) void knn_mfma_kernel(const ushort* __restrict__ A16,
                                                       const float* __restrict__ sqnp,
                                                       int* __restrict__ cand,
                                                       unsigned* __restrict__ fkey) {
    __shared__ ushort qt[64 * LP];
    __shared__ ushort dbt[2][64 * LP];
    __shared__ float  sqf[2][64];
    __shared__ float  klds[256 * 20];

    const int q0    = blockIdx.x * 64;
    const int cs    = blockIdx.y;
    const int pbase = (q0 >> 12) << 12;
    const int col0  = cs * (Nn / CS);
    const int tid   = threadIdx.x;
    const int w     = tid >> 6;
    const int l     = tid & 63;
    constexpr int NCH = (Nn / CS) / 64;

    {
        int r = tid >> 2, q = tid & 3;
        const uint4* s = reinterpret_cast<const uint4*>(A16 + (size_t)(q0 + r) * 96 + q * 24);
        uint4* d = reinterpret_cast<uint4*>(qt + r * LP + q * 24);
        d[0] = s[0]; d[1] = s[1]; d[2] = s[2];
        const uint4* s2 = reinterpret_cast<const uint4*>(
            A16 + (size_t)(pbase + col0 + r) * 96 + q * 24);
        uint4* d2 = reinterpret_cast<uint4*>(dbt[0] + r * LP + q * 24);
        d2[0] = s2[0]; d2[1] = s2[1]; d2[2] = s2[2];
    }
    if (tid < 64) sqf[0][tid] = -0.5f * sqnp[pbase + col0 + tid];
    __syncthreads();

    const int qrow = w * 16 + (l & 15);
    const int koff = (l >> 4) * 8;
    const int lb4  = (l >> 4) * 4;
    bf16x8 bq[3];
    #pragma unroll
    for (int s = 0; s < 3; ++s)
        bq[s] = *reinterpret_cast<const bf16x8*>(qt + qrow * LP + koff + 32 * s);

    // packed top-12 (descending). 0x00800000 = packed(-FLT_MAX) -> always replaced.
    unsigned bd[TK];
    #pragma unroll
    for (int t = 0; t < TK; ++t) bd[t] = 0x00800000u;
    float kd = -FLT_MAX;                    // float lower bound of 12th-best

    for (int c = 0; c < NCH; ++c) {
        const int buf = c & 1;
        if (c + 1 < NCH) {
            int r = tid >> 2, q = tid & 3;
            const uint4* s = reinterpret_cast<const uint4*>(
                A16 + (size_t)(pbase + col0 + (c + 1) * 64 + r) * 96 + q * 24);
            uint4* d = reinterpret_cast<uint4*>(dbt[buf ^ 1] + r * LP + q * 24);
            d[0] = s[0]; d[1] = s[1]; d[2] = s[2];
            if (tid < 64) sqf[buf ^ 1][tid] = -0.5f * sqnp[pbase + col0 + (c + 1) * 64 + tid];
        }

        f32x4 acc[4];
        #pragma unroll
        for (int sub = 0; sub < 4; ++sub) {
            acc[sub] = *reinterpret_cast<const f32x4*>(&sqf[buf][sub * 16 + lb4]);
            #pragma unroll
            for (int s = 0; s < 3; ++s) {
                bf16x8 a = *reinterpret_cast<const bf16x8*>(
                    dbt[buf] + (sub * 16 + (l & 15)) * LP + koff + 32 * s);
                acc[sub] = __builtin_amdgcn_mfma_f32_16x16x32_bf16(a, bq[s], acc[sub], 0, 0, 0);
            }
        }

        // guard + conditional spill; packed insert deferred to actual takes
        unsigned mask = 0;
        #pragma unroll
        for (int sub = 0; sub < 4; ++sub) {
            float m = fmaxf(fmaxf(acc[sub][0], acc[sub][1]),
                            fmaxf(acc[sub][2], acc[sub][3]));
            if (m > kd) {
                *reinterpret_cast<f32x4*>(&klds[tid * 20 + sub * 4]) = acc[sub];
                unsigned mb = (acc[sub][0] > kd ? 1u : 0u) |
                              (acc[sub][1] > kd ? 2u : 0u) |
                              (acc[sub][2] > kd ? 4u : 0u) |
                              (acc[sub][3] > kd ? 8u : 0u);
                mask |= mb << (sub * 4);
            }
        }
        while (mask) {
            int s = __builtin_ctz(mask); mask &= mask - 1;
            float v = klds[tid * 20 + s];
            if (v > kd) {   // re-test (kd may have advanced)
                unsigned b   = __float_as_uint(v);
                unsigned key = ((b ^ (unsigned)(((int)b >> 31) | 0x80000000)) & ~511u)
                               | (511u - (unsigned)(c * 16 + s));
                #pragma unroll
                for (int t = 0; t < TK; ++t) {   // bubble: max/min pair per step
                    unsigned hi = key > bd[t] ? key : bd[t];
                    key         = key > bd[t] ? bd[t] : key;
                    bd[t] = hi;
                }
                unsigned u = bd[TK - 1] & ~511u;
                kd = __uint_as_float((u & 0x80000000u) ? (u ^ 0x80000000u) : ~u);
            }
        }
        __syncthreads();
    }

    const int qg = q0 + qrow;
    const size_t obase = (size_t)qg * NCROW + (cs * 4 + (l >> 4)) * TK;
    #pragma unroll
    for (int t = 0; t < TK; ++t) {
        unsigned key = bd[t];
        int pos = 511 - (int)(key & 511u);
        int c2 = pos >> 4, s2 = pos & 15;
        cand[obase + t] = col0 + c2 * 64 + ((s2 >> 2) << 4) + lb4 + (s2 & 3);
        fkey[obase + t] = key;
    }
}

// ---- np-exact rescore with gather-free packed-key prefilter + np mean ----
// Phase 0: load 96 (packed key, idx) pairs (no feature gather).
// Phase 0b: 8-way merge of sorted streams -> packed-key top-24.
// Phase 1: gather + np-exact rescore ONLY the 24 survivors.
// Phase 2: stable top-8 by (d2, idx). Phase 3: np-mimic mean.
// block 256 = 32 queries x 8 subs; grid NPTS/32.
__global__ __launch_bounds__(256) void rescore_mean_kernel(const float* __restrict__ A32,
                                                           const float* __restrict__ sqnp,
                                                           const int* __restrict__ cand,
                                                           const unsigned* __restrict__ fkey,
                                                           float* __restrict__ nb, int h) {
    __shared__ unsigned kly[32][100];  // packed keys (8 sorted streams of 12)
    __shared__ int      cly[32][100];  // candidate indices
    __shared__ int      m24[32][NSEL]; // merged top-24 indices
    __shared__ float    s24[32][NSEL]; // np-exact d2 of survivors
    __shared__ int      sidx[32][8];
    const int tid  = threadIdx.x;
    const int qloc = tid >> 3, sub = tid & 7;
    const int p    = blockIdx.x * 32 + qloc;
    const int base = (p >> 12) << 12;

    // ---- phase 0: stream pairs into LDS ----
    {
        const uint4* fs = reinterpret_cast<const uint4*>(fkey + (size_t)p * NCROW + sub * 12);
        const int4*  is = reinterpret_cast<const int4*>(cand + (size_t)p * NCROW + sub * 12);
        uint4 k0 = fs[0], k1 = fs[1], k2 = fs[2];
        int4  i0 = is[0], i1 = is[1], i2 = is[2];
        *reinterpret_cast<uint4*>(&kly[qloc][sub * 12])     = k0;
        *reinterpret_cast<uint4*>(&kly[qloc][sub * 12 + 4]) = k1;
        *reinterpret_cast<uint4*>(&kly[qloc][sub * 12 + 8]) = k2;
        *reinterpret_cast<int4*>(&cly[qloc][sub * 12])      = i0;
        *reinterpret_cast<int4*>(&cly[qloc][sub * 12 + 4])  = i1;
        *reinterpret_cast<int4*>(&cly[qloc][sub * 12 + 8])  = i2;
    }
    __syncthreads();

    // ---- phase 0b: top-24 by (packed key DESC, idx ASC) — 8-way list merge ----
    if (sub == 0) {
        unsigned hp = 0;
        #pragma unroll 1
        for (int t = 0; t < NSEL; ++t) {
            unsigned bk = 0; int bs = 0, bidx = 0x7fffffff; bool any = false;
            #pragma unroll
            for (int s = 0; s < 8; ++s) {
                int hs = (hp >> (4 * s)) & 15;
                if (hs < 12) {
                    unsigned k = kly[qloc][s * 12 + hs];
                    int      i = cly[qloc][s * 12 + hs];
                    if (!any || k > bk || (k == bk && i < bidx)) {
                        bk = k; bs = s; bidx = i; any = true;
                    }
                }
            }
            m24[qloc][t] = bidx;
            hp += 1u << (4 * bs);
        }
    }
    __syncthreads();

    // ---- phase 1: np-exact rescore of the 24 survivors (3 per sub) ----
    {
        float4 xnr[24];
        const float4* xs = reinterpret_cast<const float4*>(A32 + (size_t)(p * Ll + h) * Cc);
        #pragma unroll
        for (int i = 0; i < 24; ++i) xnr[i] = xs[i];
        const float sqn = sqnp[p];
        #pragma unroll
        for (int c = 0; c < NSEL / 8; ++c) {
            int m = m24[qloc][sub * (NSEL / 8) + c];
            const float4* xm = reinterpret_cast<const float4*>(
                A32 + (size_t)((base + m) * Ll + h) * Cc);
            // np einsum dot: SSE SOP — 4-lane mul+add accumulators, hadd combine
            float l0 = 0.f, l1 = 0.f, l2 = 0.f, l3 = 0.f;
            #pragma unroll
            for (int t = 0; t < 24; ++t) {
                float4 a = xnr[t], b = xm[t];
                l0 = __fadd_rn(l0, __fmul_rn(a.x, b.x));
                l1 = __fadd_rn(l1, __fmul_rn(a.y, b.y));
                l2 = __fadd_rn(l2, __fmul_rn(a.z, b.z));
                l3 = __fadd_rn(l3, __fmul_rn(a.w, b.w));
            }
            float dot = __fadd_rn(__fadd_rn(l0, l1), __fadd_rn(l2, l3));
            // np: d2 = fl(fl(sq_n + sq_m) - fl(2*dot))
            s24[qloc][sub * (NSEL / 8) + c] =
                __fsub_rn(__fadd_rn(sqn, sqnp[base + m]), __fmul_rn(2.0f, dot));
        }
    }
    __syncthreads();

    // ---- phase 2: stable top-8 by (d2, idx) — lax.top_k tie semantics ----
    if (sub == 0) {
        float sd[8]; int si[8];
        #pragma unroll
        for (int t = 0; t < 8; ++t) { sd[t] = FLT_MAX; si[t] = 0x7fffffff; }
        #pragma unroll 1
        for (int c = 0; c < NSEL; ++c) lexins<8>(s24[qloc][c], m24[qloc][c], sd, si);
        #pragma unroll
        for (int t = 0; t < 8; ++t) sidx[qloc][t] = si[t];
    }
    __syncthreads();

    // ---- phase 3: np-mimic mean (pairwise-8 tree, x0.125) ----
    {
        float4 rv[8][3];
        #pragma unroll
        for (int k = 0; k < 8; ++k) {
            const float4* rs = reinterpret_cast<const float4*>(
                A32 + (size_t)((base + sidx[qloc][k]) * Ll + h) * Cc + sub * 12);
            rv[k][0] = rs[0]; rv[k][1] = rs[1]; rv[k][2] = rs[2];
        }
        float4* dst = reinterpret_cast<float4*>(nb + (size_t)p * Cc + sub * 12);
        #pragma unroll
        for (int g = 0; g < 3; ++g) {
            float4 o;
            #define NPMEAN(comp) { \
                float L_ = __fadd_rn(__fadd_rn(rv[0][g].comp, rv[1][g].comp), \
                                     __fadd_rn(rv[2][g].comp, rv[3][g].comp)); \
                float R_ = __fadd_rn(__fadd_rn(rv[4][g].comp, rv[5][g].comp), \
                                     __fadd_rn(rv[6][g].comp, rv[7][g].comp)); \
                o.comp = __fmul_rn(__fadd_rn(L_, R_), 0.125f); }
            NPMEAN(x) NPMEAN(y) NPMEAN(z) NPMEAN(w)
            #undef NPMEAN
            dst[g] = o;
        }
    }
}

// ---- np-mimic MLP GEMM: out = act(A @ W^T + bias); BLAS-style sequential-k FMA.
// W tile staged in LDS ONCE per 16 rows (4 rows/thread). FP chain per (i,j)
// IDENTICAL to the scalar version. grid (ceil(N/64), M/16), block (64,4).
template<int K, bool LEAKY>
__global__ __launch_bounds__(256) void npgemm_kernel(const float* __restrict__ A,
                                                     const float* __restrict__ W,
                                                     const float* __restrict__ bias,
                                                     float* __restrict__ out,
                                                     int N, int ostride) {
    constexpr int PW = (K == 96) ? 100 : 196;   // padded row stride (mult of 4)
    __shared__ float w_t[64 * PW];
    const int tx = threadIdx.x, ty = threadIdx.y;
    const int col0 = blockIdx.x * 64;
    const int j = col0 + tx;
    const int i0 = blockIdx.y * 16 + ty * 4;    // 4 consecutive rows per thread
    {
        int tid = ty * 64 + tx;
        int r = tid >> 2, q = tid & 3;
        constexpr int G = K / 16;               // float4 groups per quarter-thread
        float4* dst = reinterpret_cast<float4*>(&w_t[r * PW]) + q * G;
        if (col0 + r < N) {
            const float4* src = reinterpret_cast<const float4*>(
                W + (size_t)(col0 + r) * K) + q * G;
            #pragma unroll
            for (int m = 0; m < G; ++m) dst[m] = src[m];
        } else {
            #pragma unroll
            for (int m = 0; m < G; ++m) dst[m] = float4{0.f, 0.f, 0.f, 0.f};
        }
    }
    __syncthreads();
    if (j < N) {
        #pragma unroll
        for (int rr = 0; rr < 4; ++rr) {
            const float* a = A + (size_t)(i0 + rr) * K;   // wave-uniform row
            float acc = 0.f;
            #pragma unroll
            for (int k4 = 0; k4 < K / 4; ++k4) {
                float4 wv = *reinterpret_cast<const float4*>(&w_t[tx * PW + k4 * 4]);
                float4 av = *reinterpret_cast<const float4*>(a + k4 * 4);
                acc = __builtin_fmaf(av.x, wv.x, acc);
                acc = __builtin_fmaf(av.y, wv.y, acc);
                acc = __builtin_fmaf(av.z, wv.z, acc);
                acc = __builtin_fmaf(av.w, wv.w, acc);
            }
            float v = __fadd_rn(acc, bias[j]);
            if (LEAKY) v = v > 0.f ? v : __fmul_rn(0.2f, v);
            out[(size_t)(i0 + rr) * ostride + j] = v;
        }
    }
}

// ---- swizzled fp32 tile staging for value-path gemm ----
__device__ inline void stage_row(const float* __restrict__ src, float* __restrict__ tile,
                                 int r, int q) {
    const int s = (r >> 2) & 7;
    #pragma unroll
    for (int m = 0; m < 6; ++m) {
        int g = q * 6 + m;
        float4 v = reinterpret_cast<const float4*>(src)[g];
        *reinterpret_cast<float4*>(&tile[r * KP + ((g ^ s) << 2)]) = v;
    }
}

// ---------------- fast fp32 GEMM (value path): out = Ain @ W^T + bias ----------------
template<int K>
__global__ __launch_bounds__(256) void gemm_kernel(const float* __restrict__ Ain,
                                                   const float* __restrict__ W,
                                                   const float* __restrict__ bias,
                                                   float* __restrict__ out,
                                                   int Nout, int out_stride) {
    __shared__ float a_t[64 * KP];
    __shared__ float w_t[64 * KP];
    const int row0 = blockIdx.x * 64;
    const int col0 = blockIdx.y * 64;
    const int tid  = threadIdx.x;
    const int tx   = tid & 15;
    const int ty   = tid >> 4;

    float acc[4][4] = {};
    for (int kt = 0; kt < K; kt += 96) {
        __syncthreads();
        {
            int r = tid >> 2, q = tid & 3;
            stage_row(Ain + (size_t)(row0 + r) * K + kt, a_t, r, q);
            if (col0 + r < Nout) {
                stage_row(W + (size_t)(col0 + r) * K + kt, w_t, r, q);
            } else {
                const int s = (r >> 2) & 7;
                #pragma unroll
                for (int m = 0; m < 6; ++m) {
                    int g = q * 6 + m;
                    *reinterpret_cast<float4*>(&w_t[r * KP + ((g ^ s) << 2)]) =
                        float4{0.f, 0.f, 0.f, 0.f};
                }
            }
        }
        __syncthreads();
        const int sa = ty & 7, sb = tx & 7;
        #pragma unroll 4
        for (int k4 = 0; k4 < 24; ++k4) {
            float4 av[4], bv[4];
            const int ga = (k4 ^ sa) << 2, gb = (k4 ^ sb) << 2;
            #pragma unroll
            for (int i = 0; i < 4; ++i)
                av[i] = *reinterpret_cast<const float4*>(&a_t[(ty * 4 + i) * KP + ga]);
            #pragma unroll
            for (int j = 0; j < 4; ++j)
                bv[j] = *reinterpret_cast<const float4*>(&w_t[(tx * 4 + j) * KP + gb]);
            #pragma unroll
            for (int i = 0; i < 4; ++i)
                #pragma unroll
                for (int j = 0; j < 4; ++j)
                    acc[i][j] += av[i].x * bv[j].x + av[i].y * bv[j].y +
                                 av[i].z * bv[j].z + av[i].w * bv[j].w;
        }
    }
    #pragma unroll
    for (int i = 0; i < 4; ++i) {
        int row = row0 + ty * 4 + i;
        #pragma unroll
        for (int j = 0; j < 4; ++j) {
            int col = col0 + tx * 4 + j;
            if (col < Nout)
                out[(size_t)row * out_stride + col] = acc[i][j] + bias[col];
        }
    }
}

// ---------------- per-(point, head) MHA; mean over 4 slots folded in ----------------
__global__ __launch_bounds__(64) void attn_kernel(const float* __restrict__ qkv,
                                                  float* __restrict__ mbuf) {
    int t  = blockIdx.x * 64 + threadIdx.x;
    int p  = t / 3;
    int hh = t - p * 3;
    const float* base = qkv + (size_t)p * 4 * 288;
    const float* qb = base + hh * 32;
    const float* kb = base + 96 + hh * 32;
    const float* vb = base + 192 + hh * 32;

    float sc[4][4] = {};
    #pragma unroll
    for (int d = 0; d < 32; d += 4) {
        float4 qv[4], kv[4];
        #pragma unroll
        for (int l = 0; l < 4; ++l) {
            qv[l] = *reinterpret_cast<const float4*>(qb + l * 288 + d);
            kv[l] = *reinterpret_cast<const float4*>(kb + l * 288 + d);
        }
        #pragma unroll
        for (int l = 0; l < 4; ++l)
            #pragma unroll
            for (int m = 0; m < 4; ++m)
                sc[l][m] += qv[l].x * kv[m].x + qv[l].y * kv[m].y +
                            qv[l].z * kv[m].z + qv[l].w * kv[m].w;
    }
    const float scale = 0.17677669529663687f;   // 1/sqrt(32)
    float am[4] = {0.f, 0.f, 0.f, 0.f};
    #pragma unroll
    for (int l = 0; l < 4; ++l) {
        float s0 = sc[l][0] * scale, s1 = sc[l][1] * scale;
        float s2 = sc[l][2] * scale, s3 = sc[l][3] * scale;
        float mx = fmaxf(fmaxf(s0, s1), fmaxf(s2, s3));
        float e0 = expf(s0 - mx), e1 = expf(s1 - mx);
        float e2 = expf(s2 - mx), e3 = expf(s3 - mx);
        float inv = 1.f / (e0 + e1 + e2 + e3);
        am[0] += e0 * inv; am[1] += e1 * inv; am[2] += e2 * inv; am[3] += e3 * inv;
    }
    am[0] *= 0.25f; am[1] *= 0.25f; am[2] *= 0.25f; am[3] *= 0.25f;
    #pragma unroll
    for (int d = 0; d < 32; d += 4) {
        float4 o = {0.f, 0.f, 0.f, 0.f};
        #pragma unroll
        for (int m = 0; m < 4; ++m) {
            float4 v = *reinterpret_cast<const float4*>(vb + m * 288 + d);
            o.x += am[m] * v.x; o.y += am[m] * v.y;
            o.z += am[m] * v.z; o.w += am[m] * v.w;
        }
        *reinterpret_cast<float4*>(mbuf + (size_t)p * 96 + hh * 32 + d) = o;
    }
}

}  // namespace

extern "C" void kernel_launch(void* const* d_in, const int* in_sizes, int n_in,
                              void* d_out, int out_size, void* d_ws, size_t ws_size,
                              hipStream_t stream) {
    const float* xyz = (const float*)d_in[0];
    const float* W1  = (const float*)d_in[1];
    const float* b1  = (const float*)d_in[2];
    const float* W2  = (const float*)d_in[3];
    const float* b2  = (const float*)d_in[4];
    const float* ipw = (const float*)d_in[5];
    const float* ipb = (const float*)d_in[6];
    const float* opw = (const float*)d_in[7];
    const float* opb = (const float*)d_in[8];

    char* ws = (char*)d_ws;
    float*    A32  = (float*)ws;                   // [65536][96]           25.2 MB
    float*    sqnp = (float*)(ws + 25165824);      // [16384]                64 KB
    int*      cand = (int*)  (ws + 25231360);      // [16384][96]           6.3 MB
    float*    nb   = (float*)(ws + 32047104);      // [16384][96]           6.3 MB
    float*    h1   = (float*)(ws + 38338560);      // [16384][192]         12.6 MB
    float*    qkvc = (float*)(ws + 50921472);      // [16384][288]         18.9 MB
    float*    mbuf = (float*)(ws + 69795840);      // [16384][96]           6.3 MB
    ushort*   A16  = (ushort*)(ws + 76087296);     // [16384][96] bf16      3.1 MB
    unsigned* fkey = (unsigned*)(ws + 79233024);   // [16384][96] packed    6.3 MB
    // hop-phase footprint ~85.5 MB

    for (int h = 0; h < 3; ++h) {
        if (h == 0)
            sqcvt_kernel<true><<<256, 64, 0, stream>>>(xyz, A32, sqnp, A16, 0);
        else
            sqcvt_kernel<false><<<256, 64, 0, stream>>>(A32, A32, sqnp, A16, h);
        knn_mfma_kernel<<<dim3(NPTS / 64, CS), 256, 0, stream>>>(A16, sqnp, cand, fkey);
        rescore_mean_kernel<<<NPTS / 32, 256, 0, stream>>>(A32, sqnp, cand, fkey, nb, h);
        npgemm_kernel<96, true><<<dim3(3, NPTS / 16), dim3(64, 4), 0, stream>>>(
            nb, W1 + (size_t)h * 192 * 96, b1 + h * 192, h1, 192, 192);
        npgemm_kernel<192, false><<<dim3(2, NPTS / 16), dim3(64, 4), 0, stream>>>(
            h1, W2 + (size_t)h * 96 * 192, b2 + h * 96, A32 + (h + 1) * 96, 96, Ll * Cc);
    }

    // MHA: merged single-launch path if workspace allows (hop buffers dead)
    const size_t need = 100728832ull + 6291456ull;   // qkvc4 end + mbuf4
    if (ws_size >= need) {
        float* qkvc4 = (float*)(ws + 25231360);      // [65536][288]  75.5 MB
        float* mbuf4 = (float*)(ws + 100728832);     // [16384][96]    6.3 MB
        gemm_kernel<96><<<dim3(65536 / 64, 5), 256, 0, stream>>>(
            A32, ipw, ipb, qkvc4, 288, 288);
        attn_kernel<<<NPTS * 3 / 64, 64, 0, stream>>>(qkvc4, mbuf4);
        gemm_kernel<96><<<dim3(NPTS / 64, 2), 256, 0, stream>>>(
            mbuf4, opw, opb, (float*)d_out, 96, 96);
    } else {
        for (int b = 0; b < Bb; ++b) {
            gemm_kernel<96><<<dim3(16384 / 64, 5), 256, 0, stream>>>(
                A32 + (size_t)b * 4096 * Ll * Cc, ipw, ipb, qkvc, 288, 288);
            attn_kernel<<<192, 64, 0, stream>>>(qkvc, mbuf + (size_t)b * 4096 * 96);
        }
        gemm_kernel<96><<<dim3(NPTS / 64, 2), 256, 0, stream>>>(
            mbuf, opw, opb, (float*)d_out, 96, 96);
    }
}